// Round 1
// baseline (1036.768 us; speedup 1.0000x reference)
//
#include <hip/hip_runtime.h>
#include <cstdint>
#include <cstddef>

// Problem constants (match reference)
#define NN 50000
#define EE 800000
#define FIN 32
#define EDD 10
#define GG 512
#define CC 64
static constexpr float EPSV = 1e-5f;

__device__ __forceinline__ float lrelu(float x, float s) { return x > 0.f ? x : s * x; }

// ---------------- preprocessing ----------------
__global__ void k_count(const int* __restrict__ dst, int* __restrict__ deg) {
  int e = blockIdx.x * blockDim.x + threadIdx.x;
  if (e < EE) atomicAdd(&deg[dst[e]], 1);
}

// single-block exclusive scan of deg[NN] -> row_off[NN+1]
__global__ void k_scan(const int* __restrict__ deg, int* __restrict__ row_off) {
  __shared__ int sm[1024];
  int tid = threadIdx.x;
  constexpr int CPT = (NN + 1023) / 1024;  // 49
  int b = tid * CPT;
  int local[CPT];
  int s = 0;
  for (int j = 0; j < CPT; ++j) {
    int i = b + j;
    int v = (i < NN) ? deg[i] : 0;
    local[j] = s;  // exclusive prefix within thread
    s += v;
  }
  sm[tid] = s;
  __syncthreads();
  for (int off = 1; off < 1024; off <<= 1) {
    int t = (tid >= off) ? sm[tid - off] : 0;
    __syncthreads();
    sm[tid] += t;
    __syncthreads();
  }
  int base = (tid > 0) ? sm[tid - 1] : 0;
  for (int j = 0; j < CPT; ++j) {
    int i = b + j;
    if (i < NN) row_off[i] = base + local[j];
  }
  if (tid == 1023) row_off[NN] = sm[1023];  // == EE
}

__global__ void k_fill(const int* __restrict__ src, const int* __restrict__ dst,
                       const int* __restrict__ row_off, int* __restrict__ cursor,
                       int* __restrict__ perm, int* __restrict__ src_sorted) {
  int e = blockIdx.x * blockDim.x + threadIdx.x;
  if (e >= EE) return;
  int d = dst[e];
  int pos = row_off[d] + atomicAdd(&cursor[d], 1);
  perm[pos] = e;
  src_sorted[pos] = src[e];
}

// loop_ea[n][:] = mean of incoming ea rows (0 if deg==0)
__global__ void k_loop_ea(const float* __restrict__ ea, const int* __restrict__ perm,
                          const int* __restrict__ row_off, float* __restrict__ loop_ea) {
  int n = blockIdx.x * blockDim.x + threadIdx.x;
  if (n >= NN) return;
  int beg = row_off[n], end = row_off[n + 1];
  float s[EDD];
#pragma unroll
  for (int d = 0; d < EDD; ++d) s[d] = 0.f;
  for (int i = beg; i < end; ++i) {
    const float* r = ea + (size_t)perm[i] * EDD;
#pragma unroll
    for (int d = 0; d < EDD; ++d) s[d] += r[d];
  }
  float inv = 1.f / (float)max(end - beg, 1);
#pragma unroll
  for (int d = 0; d < EDD; ++d) loop_ea[n * EDD + d] = s[d] * inv;
}

// ---------------- per-layer kernels ----------------
// xw = in[N,K] @ W[K,M]; N multiple of 16
template <int K, int M>
__global__ void k_gemm(const float* __restrict__ in, const float* __restrict__ W,
                       float* __restrict__ out) {
  constexpr int BR = 16;
  constexpr int GRP = 256 / M;   // 1 (M=256) or 2 (M=128)
  constexpr int RPT = BR / GRP;  // 16 or 8
  __shared__ float xs[BR][K];
  int tid = threadIdx.x;
  int rbase = blockIdx.x * BR;
  for (int j = tid; j < BR * K; j += 256)
    xs[j / K][j % K] = in[(size_t)(rbase + j / K) * K + (j % K)];
  __syncthreads();
  int col = tid % M;
  int rg = tid / M;
  float acc[RPT];
#pragma unroll
  for (int r = 0; r < RPT; ++r) acc[r] = 0.f;
  for (int k = 0; k < K; ++k) {
    float wv = W[k * M + col];
#pragma unroll
    for (int r = 0; r < RPT; ++r) acc[r] += xs[rg * RPT + r][k] * wv;
  }
#pragma unroll
  for (int r = 0; r < RPT; ++r)
    out[(size_t)(rbase + rg * RPT + r) * M + col] = acc[r];
}

// asrc[n,h] = <xw[n,h,:], as[h,:]>, adst likewise. One wave per (n,h).
template <int H>
__global__ void k_attn_sd(const float* __restrict__ xw, const float* __restrict__ as_,
                          const float* __restrict__ ad_, float* __restrict__ asrc,
                          float* __restrict__ adst) {
  int wid = threadIdx.x >> 6, lane = threadIdx.x & 63;
  int idx = blockIdx.x * 4 + wid;
  if (idx >= NN * H) return;
  int n = idx / H, h = idx % H;
  float v = xw[(size_t)n * (H * CC) + h * CC + lane];
  float s1 = v * as_[h * CC + lane];
  float s2 = v * ad_[h * CC + lane];
#pragma unroll
  for (int off = 32; off > 0; off >>= 1) {
    s1 += __shfl_xor(s1, off);
    s2 += __shfl_xor(s2, off);
  }
  if (lane == 0) { asrc[idx] = s1; adst[idx] = s2; }
}

// we_ae[d][h] = sum_c We[d, h*C+c] * ae[h,c]
template <int H>
__global__ void k_weae(const float* __restrict__ We, const float* __restrict__ ae,
                       float* __restrict__ we_ae) {
  int t = threadIdx.x;
  if (t < EDD * H) {
    int d = t / H, h = t % H;
    float s = 0.f;
    for (int c = 0; c < CC; ++c) s += We[d * (H * CC) + h * CC + c] * ae[h * CC + c];
    we_ae[t] = s;
  }
}

// aedge[e][h] = ea[e,:] @ we_ae ; aedge_loop[n][h] = loop_ea[n,:] @ we_ae
template <int H>
__global__ void k_aedge(const float* __restrict__ ea, const float* __restrict__ loop_ea,
                        const float* __restrict__ we_ae, float* __restrict__ aedge,
                        float* __restrict__ aedge_loop) {
  __shared__ float wsm[EDD * H];
  if (threadIdx.x < EDD * H) wsm[threadIdx.x] = we_ae[threadIdx.x];
  __syncthreads();
  int idx = blockIdx.x * blockDim.x + threadIdx.x;
  const float* row;
  float* outp;
  if (idx < EE) {
    row = ea + (size_t)idx * EDD;
    outp = aedge + (size_t)idx * H;
  } else if (idx < EE + NN) {
    int n = idx - EE;
    row = loop_ea + (size_t)n * EDD;
    outp = aedge_loop + (size_t)n * H;
  } else
    return;
  float r[EDD];
#pragma unroll
  for (int d = 0; d < EDD; ++d) r[d] = row[d];
#pragma unroll
  for (int h = 0; h < H; ++h) {
    float s = 0.f;
#pragma unroll
    for (int d = 0; d < EDD; ++d) s += r[d] * wsm[d * H + h];
    outp[h] = s;
  }
}

// The fused GAT node kernel: one wave per node. lane = output channel.
template <int H>
__global__ void k_node(const float* __restrict__ xw, const float* __restrict__ asrc,
                       const float* __restrict__ adst, const float* __restrict__ aedge,
                       const float* __restrict__ aedge_loop, const int* __restrict__ row_off,
                       const int* __restrict__ src_sorted, const int* __restrict__ perm,
                       const float* __restrict__ bias, float* __restrict__ out) {
  int wid = threadIdx.x >> 6, lane = threadIdx.x & 63;
  int n = blockIdx.x * 4 + wid;
  if (n >= NN) return;
  int beg = row_off[n], end = row_off[n + 1];
  float adh[H], sl[H], m[H];
#pragma unroll
  for (int h = 0; h < H; ++h) {
    float a = asrc[n * H + h];
    adh[h] = adst[n * H + h];
    sl[h] = lrelu(a + adh[h] + aedge_loop[n * H + h], 0.2f);
    m[h] = sl[h];
  }
  // pass 1: max over incoming edges (self-loop already seeded)
  for (int i = beg + lane; i < end; i += 64) {
    int s = src_sorted[i];
    int p = perm[i];
#pragma unroll
    for (int h = 0; h < H; ++h) {
      float l = lrelu(asrc[s * H + h] + adh[h] + aedge[(size_t)p * H + h], 0.2f);
      m[h] = fmaxf(m[h], l);
    }
  }
#pragma unroll
  for (int off = 32; off > 0; off >>= 1)
#pragma unroll
    for (int h = 0; h < H; ++h) m[h] = fmaxf(m[h], __shfl_xor(m[h], off));
  // pass 2: exp, denom partials, fused aggregation  (alpha = p/denom applied at end)
  float acc[H], dpart[H];
#pragma unroll
  for (int h = 0; h < H; ++h) { acc[h] = 0.f; dpart[h] = 0.f; }
  for (int cb = beg; cb < end; cb += 64) {
    int i = cb + lane;
    float pex[H];
    int s = 0;
    if (i < end) {
      s = src_sorted[i];
      int p = perm[i];
#pragma unroll
      for (int h = 0; h < H; ++h) {
        float l = lrelu(asrc[s * H + h] + adh[h] + aedge[(size_t)p * H + h], 0.2f);
        pex[h] = __expf(l - m[h]);
        dpart[h] += pex[h];
      }
    } else {
#pragma unroll
      for (int h = 0; h < H; ++h) pex[h] = 0.f;
    }
    int cnt = min(64, end - cb);
    for (int j = 0; j < cnt; ++j) {
      int sj = __shfl(s, j);
      const float* xr = xw + (size_t)sj * (H * CC) + lane;
#pragma unroll
      for (int h = 0; h < H; ++h) {
        float pj = __shfl(pex[h], j);
        acc[h] += pj * xr[h * CC];
      }
    }
  }
#pragma unroll
  for (int off = 32; off > 0; off >>= 1)
#pragma unroll
    for (int h = 0; h < H; ++h) dpart[h] += __shfl_xor(dpart[h], off);
  const float* xn = xw + (size_t)n * (H * CC) + lane;
  float o = 0.f;
#pragma unroll
  for (int h = 0; h < H; ++h) {
    float ps = __expf(sl[h] - m[h]);
    float denom = dpart[h] + ps;
    float a = acc[h] + ps * xn[h * CC];
    o += a / denom;
  }
  out[(size_t)n * CC + lane] = o * (1.f / H) + bias[lane];
}

// ---------------- BatchNorm ----------------
__global__ void k_bn_partial(const float* __restrict__ x, float* __restrict__ psum,
                             float* __restrict__ psum2, int rows_per_block) {
  int c = threadIdx.x & 63;
  int rsub = threadIdx.x >> 6;
  int r0 = blockIdx.x * rows_per_block;
  int r1 = min(r0 + rows_per_block, NN);
  float s = 0.f, s2 = 0.f;
  for (int r = r0 + rsub; r < r1; r += 4) {
    float v = x[(size_t)r * CC + c];
    s += v;
    s2 += v * v;
  }
  __shared__ float sm[256], sm2[256];
  sm[threadIdx.x] = s;
  sm2[threadIdx.x] = s2;
  __syncthreads();
  if (rsub == 0) {
    s = sm[c] + sm[64 + c] + sm[128 + c] + sm[192 + c];
    s2 = sm2[c] + sm2[64 + c] + sm2[128 + c] + sm2[192 + c];
    psum[blockIdx.x * CC + c] = s;
    psum2[blockIdx.x * CC + c] = s2;
  }
}

__global__ void k_bn_final(const float* __restrict__ psum, const float* __restrict__ psum2,
                           const float* __restrict__ g, const float* __restrict__ be,
                           float* __restrict__ scale, float* __restrict__ shift, int nblk) {
  int c = threadIdx.x;
  if (c >= CC) return;
  float s = 0.f, s2 = 0.f;
  for (int b = 0; b < nblk; ++b) {
    s += psum[b * CC + c];
    s2 += psum2[b * CC + c];
  }
  float mu = s / (float)NN;
  float var = s2 / (float)NN - mu * mu;
  float sc = g[c] * rsqrtf(var + EPSV);
  scale[c] = sc;
  shift[c] = be[c] - mu * sc;
}

__global__ void k_bn_apply(float* __restrict__ x, const float* __restrict__ scale,
                           const float* __restrict__ shift, float slope) {
  int i = blockIdx.x * blockDim.x + threadIdx.x;
  if (i >= NN * CC) return;
  int c = i & 63;
  float v = x[i] * scale[c] + shift[c];
  x[i] = lrelu(v, slope);  // slope=0 -> relu
}

// ---------------- pooling + head ----------------
__global__ void k_pool(const float* __restrict__ h, const int* __restrict__ batch,
                       float* __restrict__ pooled, float* __restrict__ gcnt) {
  int i = blockIdx.x * blockDim.x + threadIdx.x;
  if (i >= NN * CC) return;
  int n = i >> 6, c = i & 63;
  int g = batch[n];
  atomicAdd(&pooled[g * CC + c], h[i]);
  if (c == 0) atomicAdd(&gcnt[g], 1.f);
}

__global__ void k_head(const float* __restrict__ pooled, const float* __restrict__ gcnt,
                       const float* __restrict__ fw1, const float* __restrict__ fb1,
                       const float* __restrict__ fw2, const float* __restrict__ fb2,
                       float* __restrict__ out) {
  int g = blockIdx.x;
  int j = threadIdx.x;  // 64
  float inv = 1.f / fmaxf(gcnt[g], 1.f);
  float h1 = fb1[j];
  for (int k = 0; k < CC; ++k) h1 += (pooled[g * CC + k] * inv) * fw1[k * CC + j];
  h1 = fmaxf(h1, 0.f);
  float o = h1 * fw2[j];
#pragma unroll
  for (int off = 32; off > 0; off >>= 1) o += __shfl_xor(o, off);
  if (j == 0) out[g] = o + fb2[0];
}

// ---------------- launch ----------------
extern "C" void kernel_launch(void* const* d_in, const int* in_sizes, int n_in,
                              void* d_out, int out_size, void* d_ws, size_t ws_size,
                              hipStream_t stream) {
  const float* x = (const float*)d_in[0];
  const int* eidx = (const int*)d_in[1];
  const float* ea = (const float*)d_in[2];
  const int* batch = (const int*)d_in[3];
  const float* w[3] = {(const float*)d_in[4], (const float*)d_in[12], (const float*)d_in[20]};
  const float* as_[3] = {(const float*)d_in[5], (const float*)d_in[13], (const float*)d_in[21]};
  const float* ad_[3] = {(const float*)d_in[6], (const float*)d_in[14], (const float*)d_in[22]};
  const float* we_[3] = {(const float*)d_in[7], (const float*)d_in[15], (const float*)d_in[23]};
  const float* ae_[3] = {(const float*)d_in[8], (const float*)d_in[16], (const float*)d_in[24]};
  const float* b_[3] = {(const float*)d_in[9], (const float*)d_in[17], (const float*)d_in[25]};
  const float* g_[3] = {(const float*)d_in[10], (const float*)d_in[18], (const float*)d_in[26]};
  const float* be_[3] = {(const float*)d_in[11], (const float*)d_in[19], (const float*)d_in[27]};
  const float* fw1 = (const float*)d_in[28];
  const float* fb1 = (const float*)d_in[29];
  const float* fw2 = (const float*)d_in[30];
  const float* fb2 = (const float*)d_in[31];
  const int* srcp = eidx;       // edge_index row 0
  const int* dstp = eidx + EE;  // edge_index row 1

  // workspace carve (total ~101 MB)
  char* base = (char*)d_ws;
  size_t off = 0;
  auto alloc = [&](size_t bytes) {
    void* p = base + off;
    off = (off + bytes + 255) & ~(size_t)255;
    return p;
  };
  int* deg_i = (int*)alloc((size_t)NN * 4);
  int* row_off = (int*)alloc((size_t)(NN + 1) * 4);
  int* cursor = (int*)alloc((size_t)NN * 4);
  int* perm = (int*)alloc((size_t)EE * 4);
  int* src_sorted = (int*)alloc((size_t)EE * 4);
  float* loop_ea = (float*)alloc((size_t)NN * EDD * 4);
  float* aedge = (float*)alloc((size_t)EE * 4 * 4);
  float* aedge_loop = (float*)alloc((size_t)NN * 4 * 4);
  float* asrc = (float*)alloc((size_t)NN * 4 * 4);
  float* adst = (float*)alloc((size_t)NN * 4 * 4);
  float* xw = (float*)alloc((size_t)NN * 256 * 4);
  float* h0 = (float*)alloc((size_t)NN * CC * 4);
  float* h1 = (float*)alloc((size_t)NN * CC * 4);
  float* psum = (float*)alloc((size_t)128 * CC * 4);
  float* psum2 = (float*)alloc((size_t)128 * CC * 4);
  float* bnscale = (float*)alloc(CC * 4);
  float* bnshift = (float*)alloc(CC * 4);
  float* weae = (float*)alloc(EDD * 4 * 4);
  float* pooled = (float*)alloc((size_t)GG * CC * 4);
  float* gcnt = (float*)alloc((size_t)GG * 4);
  (void)ws_size;
  (void)in_sizes;
  (void)n_in;
  (void)out_size;

  hipMemsetAsync(deg_i, 0, (size_t)NN * 4, stream);
  hipMemsetAsync(cursor, 0, (size_t)NN * 4, stream);
  hipMemsetAsync(pooled, 0, (size_t)GG * CC * 4, stream);
  hipMemsetAsync(gcnt, 0, (size_t)GG * 4, stream);

  k_count<<<(EE + 255) / 256, 256, 0, stream>>>(dstp, deg_i);
  k_scan<<<1, 1024, 0, stream>>>(deg_i, row_off);
  k_fill<<<(EE + 255) / 256, 256, 0, stream>>>(srcp, dstp, row_off, cursor, perm, src_sorted);
  k_loop_ea<<<(NN + 127) / 128, 128, 0, stream>>>(ea, perm, row_off, loop_ea);

  const int heads[3] = {4, 2, 4};
  for (int l = 0; l < 3; ++l) {
    const float* in = (l == 0) ? x : ((l == 1) ? h0 : h1);
    float* outb = (l == 0) ? h0 : ((l == 1) ? h1 : h0);
    int H = heads[l];
    if (l == 0)
      k_gemm<FIN, 256><<<NN / 16, 256, 0, stream>>>(in, w[l], xw);
    else if (H == 2)
      k_gemm<CC, 128><<<NN / 16, 256, 0, stream>>>(in, w[l], xw);
    else
      k_gemm<CC, 256><<<NN / 16, 256, 0, stream>>>(in, w[l], xw);

    if (H == 4) {
      k_attn_sd<4><<<NN * 4 / 4, 256, 0, stream>>>(xw, as_[l], ad_[l], asrc, adst);
      k_weae<4><<<1, 64, 0, stream>>>(we_[l], ae_[l], weae);
      k_aedge<4><<<(EE + NN + 255) / 256, 256, 0, stream>>>(ea, loop_ea, weae, aedge, aedge_loop);
      k_node<4><<<(NN + 3) / 4, 256, 0, stream>>>(xw, asrc, adst, aedge, aedge_loop, row_off,
                                                  src_sorted, perm, b_[l], outb);
    } else {
      k_attn_sd<2><<<NN * 2 / 4, 256, 0, stream>>>(xw, as_[l], ad_[l], asrc, adst);
      k_weae<2><<<1, 64, 0, stream>>>(we_[l], ae_[l], weae);
      k_aedge<2><<<(EE + NN + 255) / 256, 256, 0, stream>>>(ea, loop_ea, weae, aedge, aedge_loop);
      k_node<2><<<(NN + 3) / 4, 256, 0, stream>>>(xw, asrc, adst, aedge, aedge_loop, row_off,
                                                  src_sorted, perm, b_[l], outb);
    }

    int rpb = (NN + 127) / 128;  // 391
    k_bn_partial<<<128, 256, 0, stream>>>(outb, psum, psum2, rpb);
    k_bn_final<<<1, 64, 0, stream>>>(psum, psum2, g_[l], be_[l], bnscale, bnshift, 128);
    k_bn_apply<<<(NN * CC + 255) / 256, 256, 0, stream>>>(outb, bnscale, bnshift,
                                                          (l == 2) ? 0.01f : 0.0f);
  }

  k_pool<<<(NN * CC + 255) / 256, 256, 0, stream>>>(h0, batch, pooled, gcnt);
  k_head<<<GG, 64, 0, stream>>>(pooled, gcnt, fw1, fb1, fw2, fb2, (float*)d_out);
}